// Round 8
// baseline (336.765 us; speedup 1.0000x reference)
//
#include <hip/hip_runtime.h>
#include <math.h>

#define TPB 256

// ---- LDS layout (float offsets), lifetime-overlaid. Weights in GLOBAL/L2. ----
// x   [0,1008)     padded [28][36], rows 16B-aligned, cols 28..35 zeroed
// c1  [1008,2064)  conv7 out [8][11][12]
// y   [1008,3608)  dyn out [10][13][20] (over c1)
// f   [3608,3698)  h [3698,3730) k [3730,3770)  (dead before conv2)
// P2h [3608,4968)  conv2 h1 partials [20][68] (over f/h/k after death)
// p3  [0,320) pf [320,570) a1 [570,620) z [620,630)  (x dead after dyn)
#define OX    0
#define OC1   1008
#define OY    1008
#define OF    3608
#define OH    3698
#define OK2   3730
#define OP2   3608
#define OP3   0
#define OPF   320
#define OA1   570
#define OZ    620
#define SM_TOT 4968   // 19872 B -> 8 blocks/CU = 32 waves (cap)

// NOTE: no min-waves launch bound — R3 showed forced low VGPR spills to scratch.
// R8: all hot LDS reads are ds_read_b128 on 16B-aligned padded layouts; start
// banks verified disjoint per wave (conv7 covers all 32 banks; conv2 {0,8,20,28}).
__global__ __launch_bounds__(TPB) void fused_forward(
    const float* __restrict__ x,
    const float* __restrict__ kf_w1, const float* __restrict__ kf_b1,
    const float* __restrict__ kf_w2, const float* __restrict__ kf_b2,
    const float* __restrict__ kf_fc1_w, const float* __restrict__ kf_fc1_b,
    const float* __restrict__ kf_fc2_w, const float* __restrict__ kf_fc2_b,
    const float* __restrict__ conv2_w, const float* __restrict__ conv2_b,
    const float* __restrict__ fc1_w, const float* __restrict__ fc1_b,
    const float* __restrict__ fc2_w, const float* __restrict__ fc2_b,
    float* __restrict__ out)
{
    __shared__ float sm[SM_TOT];
    const int tid = threadIdx.x;
    const int n = blockIdx.x;

    // ---- stage 0: stage x into padded LDS [28][36]; zero cols 28..35 ----
    {
        if (tid < 196) {
            const float4* xg = (const float4*)(x + (long long)n * 784);
            int r = tid / 7, c = (tid % 7) * 4;        // 28 = 7 float4 per row
            *(float4*)&sm[OX + r * 36 + c] = xg[tid];
        } else if (tid >= 200 && tid < 256) {
            int t = tid - 200;
            int r = t >> 1, c = 28 + (t & 1) * 4;
            *(float4*)&sm[OX + r * 36 + c] = make_float4(0.f, 0.f, 0.f, 0.f);
        }
    }
    __syncthreads();

    // ---- conv7 (28->22) + pool (->11) + relu ----
    // lane map: oc = tid&7 (broadcast); col halves at cc0 in {0,12} so every
    // row read is 5x ds_read_b128. h=1 writes pooled px 6..10 (5 outputs).
    if (tid < 176) {
        int oc = tid & 7;
        int r  = tid >> 3;
        int py = r >> 1;
        int h  = r & 1;
        int cc0 = 12 * h;
        float c[2][12];
        #pragma unroll
        for (int r2 = 0; r2 < 2; ++r2)
            #pragma unroll
            for (int i = 0; i < 12; ++i) c[r2][i] = 0.f;
        float wc[7], wp[7];
        const float* wg = kf_w1 + oc * 49;
        #pragma unroll
        for (int i = 0; i < 7; ++i) wc[i] = wg[i];
        #pragma unroll
        for (int t = 0; t < 8; ++t) {
            const float* xs = &sm[OX + (2 * py + t) * 36 + cc0];
            float4 q0 = *(const float4*)(xs + 0);
            float4 q1 = *(const float4*)(xs + 4);
            float4 q2 = *(const float4*)(xs + 8);
            float4 q3 = *(const float4*)(xs + 12);
            float4 q4 = *(const float4*)(xs + 16);
            float row[20] = {q0.x,q0.y,q0.z,q0.w, q1.x,q1.y,q1.z,q1.w,
                             q2.x,q2.y,q2.z,q2.w, q3.x,q3.y,q3.z,q3.w,
                             q4.x,q4.y,q4.z,q4.w};
            if (t <= 6) {
                #pragma unroll
                for (int kx = 0; kx < 7; ++kx)
                    #pragma unroll
                    for (int cc = 0; cc < 12; ++cc)
                        c[0][cc] = fmaf(wc[kx], row[cc + kx], c[0][cc]);
            }
            if (t >= 1) {
                #pragma unroll
                for (int kx = 0; kx < 7; ++kx)
                    #pragma unroll
                    for (int cc = 0; cc < 12; ++cc)
                        c[1][cc] = fmaf(wp[kx], row[cc + kx], c[1][cc]);
            }
            #pragma unroll
            for (int i = 0; i < 7; ++i) wp[i] = wc[i];
            if (t < 7) {
                const float* wn = wg + (t + 1) * 7;
                #pragma unroll
                for (int i = 0; i < 7; ++i) wc[i] = wn[i];
            }
        }
        float b = kf_b1[oc];
        #pragma unroll
        for (int j = 0; j < 6; ++j) {
            if (h == 0 || j < 5) {
                float m = fmaxf(fmaxf(c[0][2 * j], c[0][2 * j + 1]),
                                fmaxf(c[1][2 * j], c[1][2 * j + 1]));
                sm[OC1 + oc * 132 + py * 12 + 6 * h + j] = fmaxf(m + b, 0.f);
            }
        }
    }
    __syncthreads();

    // ---- conv5 (11->7 used 6x6) + pool (->3) + relu, full-depth ----
    // oc = tid%10 broadcast; scalar reads (px offset breaks b128 alignment).
    if (tid < 90) {
        int oc = tid % 10, r = tid / 10;
        int py = r / 3, px = r % 3;
        float a00 = 0.f, a01 = 0.f, a10 = 0.f, a11 = 0.f;
        for (int ic = 0; ic < 8; ++ic) {
            float w[25];
            const float* wg = kf_w2 + (oc * 8 + ic) * 25;
            #pragma unroll
            for (int i = 0; i < 25; ++i) w[i] = wg[i];
            const float* xb = &sm[OC1 + ic * 132 + (2 * py) * 12 + 2 * px];
            float cur[6], nxt[6];
            #pragma unroll
            for (int i = 0; i < 6; ++i) cur[i] = xb[i];
            #pragma unroll
            for (int ky = 0; ky < 5; ++ky) {
                const float* xr = xb + (ky + 1) * 12;
                #pragma unroll
                for (int i = 0; i < 6; ++i) nxt[i] = xr[i];
                #pragma unroll
                for (int kx = 0; kx < 5; ++kx) {
                    float wv = w[ky * 5 + kx];
                    a00 = fmaf(wv, cur[kx],     a00);
                    a01 = fmaf(wv, cur[kx + 1], a01);
                    a10 = fmaf(wv, nxt[kx],     a10);
                    a11 = fmaf(wv, nxt[kx + 1], a11);
                }
                #pragma unroll
                for (int i = 0; i < 6; ++i) cur[i] = nxt[i];
            }
        }
        float m = fmaxf(fmaxf(a00, a01), fmaxf(a10, a11)) + kf_b2[oc];
        sm[OF + oc * 9 + py * 3 + px] = fmaxf(m, 0.f);
    }
    __syncthreads();

    // ---- fc 90->32 + relu, then fc 32->40: both wave 0, no barrier between ----
    if (tid < 32) {
        float acc = kf_fc1_b[tid];
        const float* wr = &kf_fc1_w[tid * 90];
        for (int i = 0; i < 90; ++i) acc = fmaf(wr[i], sm[OF + i], acc);
        sm[OH + tid] = fmaxf(acc, 0.f);
    }
    if (tid < 40) {
        float acc = kf_fc2_b[tid];
        const float* wr = &kf_fc2_w[tid * 32];
        #pragma unroll
        for (int i = 0; i < 32; ++i) acc = fmaf(wr[i], sm[OH + i], acc);
        sm[OK2 + tid] = acc;
    }
    __syncthreads();

    // ---- dynamic 2x2 conv + pool + relu -> y [10][13][20] ----
    if (tid < 130) {
        int oc = tid % 10, py = tid / 10;
        float k0 = sm[OK2 + oc * 4 + 0], k1 = sm[OK2 + oc * 4 + 1];
        float k2 = sm[OK2 + oc * 4 + 2], k3 = sm[OK2 + oc * 4 + 3];
        const float* x0 = &sm[OX + 2 * py * 36];
        const float* x1 = x0 + 36;
        const float* x2 = x0 + 72;
        float A0 = x0[0], A1 = x1[0], A2 = x2[0];
        float B0 = x0[1], B1 = x1[1], B2 = x2[1];
        #pragma unroll
        for (int j = 0; j < 13; ++j) {
            float C0 = x0[2 * j + 2], C1 = x1[2 * j + 2], C2 = x2[2 * j + 2];
            float c00 = A0 * k0 + B0 * k1 + A1 * k2 + B1 * k3;
            float c01 = B0 * k0 + C0 * k1 + B1 * k2 + C1 * k3;
            float c10 = A1 * k0 + B1 * k1 + A2 * k2 + B2 * k3;
            float c11 = B1 * k0 + C1 * k1 + B2 * k2 + C2 * k3;
            float m = fmaxf(fmaxf(c00, c01), fmaxf(c10, c11));
            sm[OY + oc * 260 + py * 20 + j] = fmaxf(m, 0.f);
            A0 = C0; A1 = C1; A2 = C2;
            if (j < 12) { B0 = x0[2 * j + 3]; B1 = x1[2 * j + 3]; B2 = x2[2 * j + 3]; }
        }
    }
    __syncthreads();

    // ---- conv2 5x5 (8x8 used): thread = (h2, rg4, oc20); rows via 3x b128 ----
    int c2_oc = tid % 20, c2_q = tid / 20;
    int c2_h = c2_q & 1, c2_rg = c2_q >> 1;
    float acc[2][8];
    if (tid < 160) {
        int r0 = 2 * c2_rg;
        #pragma unroll
        for (int r = 0; r < 2; ++r)
            #pragma unroll
            for (int i = 0; i < 8; ++i) acc[r][i] = 0.f;
        for (int icg = 0; icg < 5; ++icg) {
            int ic = 5 * c2_h + icg;
            float w[25];
            const float* wg = conv2_w + (c2_oc * 10 + ic) * 25;
            #pragma unroll
            for (int i = 0; i < 25; ++i) w[i] = wg[i];
            const float* yb = &sm[OY + ic * 260 + r0 * 20];
            #pragma unroll
            for (int u = 0; u < 6; ++u) {
                const float* ys = yb + u * 20;
                float4 q0 = *(const float4*)(ys + 0);
                float4 q1 = *(const float4*)(ys + 4);
                float4 q2 = *(const float4*)(ys + 8);
                float row[12] = {q0.x,q0.y,q0.z,q0.w, q1.x,q1.y,q1.z,q1.w,
                                 q2.x,q2.y,q2.z,q2.w};
                #pragma unroll
                for (int rr = 0; rr < 2; ++rr) {
                    int ky = u - rr;
                    if (ky >= 0 && ky <= 4) {
                        #pragma unroll
                        for (int kx = 0; kx < 5; ++kx)
                            #pragma unroll
                            for (int cx = 0; cx < 8; ++cx)
                                acc[rr][cx] = fmaf(w[ky * 5 + kx], row[cx + kx], acc[rr][cx]);
                    }
                }
            }
        }
        if (c2_h == 1) {   // h1 lanes park partials in LDS (4x b128)
            int base = OP2 + c2_oc * 68 + c2_rg * 16;
            *(float4*)&sm[base + 0]  = make_float4(acc[0][0], acc[0][1], acc[0][2], acc[0][3]);
            *(float4*)&sm[base + 4]  = make_float4(acc[0][4], acc[0][5], acc[0][6], acc[0][7]);
            *(float4*)&sm[base + 8]  = make_float4(acc[1][0], acc[1][1], acc[1][2], acc[1][3]);
            *(float4*)&sm[base + 12] = make_float4(acc[1][4], acc[1][5], acc[1][6], acc[1][7]);
        }
    }
    __syncthreads();

    // ---- h0 lanes: combine partner partials + bias + pool + relu -> p3 ----
    if (tid < 160 && c2_h == 0) {
        int base = OP2 + c2_oc * 68 + c2_rg * 16;
        float4 p0 = *(const float4*)&sm[base + 0];
        float4 p1 = *(const float4*)&sm[base + 4];
        float4 p2 = *(const float4*)&sm[base + 8];
        float4 p3v = *(const float4*)&sm[base + 12];
        float s0[8] = {acc[0][0]+p0.x, acc[0][1]+p0.y, acc[0][2]+p0.z, acc[0][3]+p0.w,
                       acc[0][4]+p1.x, acc[0][5]+p1.y, acc[0][6]+p1.z, acc[0][7]+p1.w};
        float s1[8] = {acc[1][0]+p2.x, acc[1][1]+p2.y, acc[1][2]+p2.z, acc[1][3]+p2.w,
                       acc[1][4]+p3v.x, acc[1][5]+p3v.y, acc[1][6]+p3v.z, acc[1][7]+p3v.w};
        float b = conv2_b[c2_oc];
        #pragma unroll
        for (int px = 0; px < 4; ++px) {
            float m = fmaxf(fmaxf(s0[2*px], s0[2*px+1]), fmaxf(s1[2*px], s1[2*px+1]));
            sm[OP3 + c2_oc * 16 + c2_rg * 4 + px] = fmaxf(m + b, 0.f);
        }
    }
    __syncthreads();

    // ---- fc 320->50, 5-way k-split, float4 ----
    if (tid < 250) {
        int g = tid / 50, o = tid % 50;
        const float4* wr = (const float4*)(fc1_w + o * 320 + g * 64);
        const float4* pp = (const float4*)&sm[OP3 + g * 64];
        float a = 0.f;
        #pragma unroll
        for (int i = 0; i < 16; ++i) {
            float4 wv = wr[i], pv = pp[i];
            a = fmaf(wv.x, pv.x, a); a = fmaf(wv.y, pv.y, a);
            a = fmaf(wv.z, pv.z, a); a = fmaf(wv.w, pv.w, a);
        }
        sm[OPF + tid] = a;
    }
    __syncthreads();

    // ---- tail: all wave 0, barrier-free ----
    if (tid < 50) {
        float a = fc1_b[tid];
        #pragma unroll
        for (int g = 0; g < 5; ++g) a += sm[OPF + g * 50 + tid];
        sm[OA1 + tid] = fmaxf(a, 0.f);
    }
    if (tid < 10) {
        float a = fc2_b[tid];
        const float* wr = &fc2_w[tid * 50];
        #pragma unroll
        for (int i = 0; i < 50; ++i) a = fmaf(wr[i], sm[OA1 + i], a);
        sm[OZ + tid] = a;
    }
    if (tid < 10) {
        float m = sm[OZ + 0];
        #pragma unroll
        for (int i = 1; i < 10; ++i) m = fmaxf(m, sm[OZ + i]);
        float s = 0.f;
        #pragma unroll
        for (int i = 0; i < 10; ++i) s += expf(sm[OZ + i] - m);
        out[n * 10 + tid] = sm[OZ + tid] - m - logf(s);
    }
}

extern "C" void kernel_launch(void* const* d_in, const int* in_sizes, int n_in,
                              void* d_out, int out_size, void* d_ws, size_t ws_size,
                              hipStream_t stream) {
    const float* x        = (const float*)d_in[0];
    const float* kf_w1    = (const float*)d_in[1];
    const float* kf_b1    = (const float*)d_in[2];
    const float* kf_w2    = (const float*)d_in[3];
    const float* kf_b2    = (const float*)d_in[4];
    const float* kf_fc1_w = (const float*)d_in[5];
    const float* kf_fc1_b = (const float*)d_in[6];
    const float* kf_fc2_w = (const float*)d_in[7];
    const float* kf_fc2_b = (const float*)d_in[8];
    const float* conv2_w  = (const float*)d_in[9];
    const float* conv2_b  = (const float*)d_in[10];
    const float* fc1_w    = (const float*)d_in[11];
    const float* fc1_b    = (const float*)d_in[12];
    const float* fc2_w    = (const float*)d_in[13];
    const float* fc2_b    = (const float*)d_in[14];

    const int N = in_sizes[0] / 784;   // 8192

    fused_forward<<<N, TPB, 0, stream>>>(
        x, kf_w1, kf_b1, kf_w2, kf_b2, kf_fc1_w, kf_fc1_b, kf_fc2_w, kf_fc2_b,
        conv2_w, conv2_b, fc1_w, fc1_b, fc2_w, fc2_b, (float*)d_out);
}